// Round 4
// baseline (267.601 us; speedup 1.0000x reference)
//
#include <hip/hip_runtime.h>

typedef unsigned short u16;
typedef unsigned int u32;
using frag8 = __attribute__((ext_vector_type(8))) short;   // 8 x bf16 (4 VGPRs)
using f32x4 = __attribute__((ext_vector_type(4))) float;   // 16x16 MFMA accumulator

// ---------- helpers ----------
__device__ __forceinline__ u16 f2bf(float f) {
  union { float f; u32 u; } x;
  x.f = f;
  u32 r = (x.u + 0x7fffu + ((x.u >> 16) & 1u)) >> 16;  // RNE
  return (u16)r;
}

// Stage a 128x64 bf16 tile (row-major, k contiguous) global -> LDS via async
// global_load_lds, width 16B. 256 threads, 4 issues each. LDS dest must be
// wave-uniform base + lane*16 (hardware constraint) so the LDS image is
// lane-ordered; we XOR-swizzle WHICH global chunk each lane fetches
// (colc ^ row&7) to break the 128B-row-stride bank aliasing. frag_read64
// applies the same XOR to find its data. [R3: SQ_LDS_BANK_CONFLICT == 0]
__device__ __forceinline__ void stage_tile64(const u16* g, int ld, u16* lds, int tid) {
  const int wv = tid >> 6;
#pragma unroll
  for (int i = 0; i < 4; ++i) {
    const int c = i * 256 + tid;              // 16B chunk index, 1024 total
    const int row = c >> 3;                   // 8 chunks per 64-elem row
    const int colc = (c & 7) ^ (row & 7);     // swizzled source chunk
    __builtin_amdgcn_global_load_lds(
        (const __attribute__((address_space(1))) void*)(g + (size_t)row * ld + colc * 8),
        (__attribute__((address_space(3))) void*)(lds + (size_t)(i * 256 + wv * 64) * 8),
        16, 0, 0);
  }
}

// 16x16x32 A/B fragment from a swizzled 128x64 tile; kk selects k-half (0/1).
__device__ __forceinline__ frag8 frag_read64(const u16* lds, int row, int kk, int quad) {
  const int cc = (kk * 4 + quad) ^ (row & 7);
  return *(const frag8*)&lds[row * 64 + cc * 8];
}

// ---------- fused prep: bf16 casts of x, Wq, Wk, Wv + exp(pos_bias) ----------
__global__ void prep_kernel(const float* __restrict__ x, const float* __restrict__ Wq,
                            const float* __restrict__ Wk, const float* __restrict__ Wv,
                            const float* __restrict__ pb, u16* __restrict__ xb,
                            u16* __restrict__ wqb, u16* __restrict__ wkb,
                            u16* __restrict__ wvb, u16* __restrict__ ewb) {
  const int blk = blockIdx.x;
  const float* src;
  u16* dst;
  int base;
  bool ex = false;
  if (blk < 16384)      { src = x;  dst = xb;  base = blk; }
  else if (blk < 16640) { src = Wq; dst = wqb; base = blk - 16384; }
  else if (blk < 16896) { src = Wk; dst = wkb; base = blk - 16640; }
  else if (blk < 17152) { src = Wv; dst = wvb; base = blk - 16896; }
  else                  { src = pb; dst = ewb; base = blk - 17152; ex = true; }
  const int i = base * 256 + threadIdx.x;
  float4 v = ((const float4*)src)[i];
  ushort4 o;
  if (ex) {
    o.x = f2bf(__expf(v.x)); o.y = f2bf(__expf(v.y));
    o.z = f2bf(__expf(v.z)); o.w = f2bf(__expf(v.w));
  } else {
    o.x = f2bf(v.x); o.y = f2bf(v.y); o.z = f2bf(v.z); o.w = f2bf(v.w);
  }
  ((ushort4*)dst)[i] = o;
}

// ---------- fused Q + KV projections, one dispatch ----------
// 2048 blocks, parity decode: even -> KV block, odd -> Q block. Q and KV have
// no data dependency; fusing removes a launch gap and lets staging-light Q
// blocks co-schedule with MFMA-heavy KV blocks on the same CU (m114 overlap).
// Q:  sigmoid(x @ Wq^T + bq) -> d_out (fp32, reread by aft_kernel)
// KV: ekT = exp(k), ekvT = exp(k)*v, both [b][d][s] bf16 (k-major for aft)
__global__ __launch_bounds__(256, 2) void qkv_kernel(const u16* __restrict__ xb,
                                                     const u16* __restrict__ wqb,
                                                     const u16* __restrict__ wkb,
                                                     const u16* __restrict__ wvb,
                                                     const float* __restrict__ bq,
                                                     const float* __restrict__ bk,
                                                     const float* __restrict__ bv,
                                                     float* __restrict__ out,
                                                     u16* __restrict__ ekT,
                                                     u16* __restrict__ ekvT) {
  __shared__ __align__(16) u16 smem[3 * 128 * 64];   // 48 KB; Q path uses 2/3
  u16* T0 = smem;
  u16* T1 = smem + 128 * 64;
  u16* T2 = smem + 2 * 128 * 64;
  const int tid = threadIdx.x;
  const int lane = tid & 63, wv = tid >> 6;
  const int wm = (wv & 1) * 64, wn = (wv >> 1) * 64;
  const int fr = lane & 15, quad = lane >> 4;
  const int blk = blockIdx.x;
  const int bi = blk >> 1;

  if (blk & 1) {
    // ---- Q block: bi in [0,1024): m0 = (bi>>2)*128 over B*N, n0 = (bi&3)*128 over D
    const int m0 = (bi >> 2) * 128;
    const int n0 = (bi & 3) * 128;
    f32x4 acc[4][4] = {};
    for (int k0 = 0; k0 < 512; k0 += 64) {
      stage_tile64(xb + (size_t)m0 * 512 + k0, 512, T0, tid);
      stage_tile64(wqb + (size_t)n0 * 512 + k0, 512, T1, tid);
      __syncthreads();
#pragma unroll
      for (int kk = 0; kk < 2; ++kk) {
        frag8 a[4], b[4];
#pragma unroll
        for (int i = 0; i < 4; ++i) {
          a[i] = frag_read64(T0, wm + i * 16 + fr, kk, quad);
          b[i] = frag_read64(T1, wn + i * 16 + fr, kk, quad);
        }
#pragma unroll
        for (int mi = 0; mi < 4; ++mi)
#pragma unroll
          for (int ni = 0; ni < 4; ++ni)
            acc[mi][ni] = __builtin_amdgcn_mfma_f32_16x16x32_bf16(a[mi], b[ni], acc[mi][ni], 0, 0, 0);
      }
      __syncthreads();
    }
#pragma unroll
    for (int mi = 0; mi < 4; ++mi)
#pragma unroll
      for (int ni = 0; ni < 4; ++ni) {
        const int col = n0 + wn + ni * 16 + fr;
        const float bqv = bq[col];
#pragma unroll
        for (int r = 0; r < 4; ++r) {
          const int row = m0 + wm + mi * 16 + quad * 4 + r;
          const float qv = acc[mi][ni][r] + bqv;
          out[(size_t)row * 512 + col] = 1.0f / (1.0f + __expf(-qv));
        }
      }
  } else {
    // ---- KV block: bi in [0,1024): b = bi>>5, d0 = ((bi>>3)&3)*128, s0 = (bi&7)*128
    const int b  = bi >> 5;
    const int d0 = ((bi >> 3) & 3) * 128;
    const int s0 = (bi & 7) * 128;
    f32x4 acck[4][4] = {}, accv[4][4] = {};
    for (int k0 = 0; k0 < 512; k0 += 64) {
      stage_tile64(wkb + (size_t)d0 * 512 + k0, 512, T0, tid);
      stage_tile64(wvb + (size_t)d0 * 512 + k0, 512, T1, tid);
      stage_tile64(xb + ((size_t)b * 1024 + s0) * 512 + k0, 512, T2, tid);
      __syncthreads();
#pragma unroll
      for (int kk = 0; kk < 2; ++kk) {
        frag8 ak[4], av[4], bb[4];
#pragma unroll
        for (int i = 0; i < 4; ++i) {
          ak[i] = frag_read64(T0, wm + i * 16 + fr, kk, quad);
          av[i] = frag_read64(T1, wm + i * 16 + fr, kk, quad);
          bb[i] = frag_read64(T2, wn + i * 16 + fr, kk, quad);
        }
#pragma unroll
        for (int mi = 0; mi < 4; ++mi)
#pragma unroll
          for (int ni = 0; ni < 4; ++ni) {
            acck[mi][ni] = __builtin_amdgcn_mfma_f32_16x16x32_bf16(ak[mi], bb[ni], acck[mi][ni], 0, 0, 0);
            accv[mi][ni] = __builtin_amdgcn_mfma_f32_16x16x32_bf16(av[mi], bb[ni], accv[mi][ni], 0, 0, 0);
          }
      }
      __syncthreads();
    }
#pragma unroll
    for (int mi = 0; mi < 4; ++mi)
#pragma unroll
      for (int r = 0; r < 4; ++r) {
        const int d = d0 + wm + mi * 16 + quad * 4 + r;
        const float bkv = bk[d], bvv = bv[d];
#pragma unroll
        for (int ni = 0; ni < 4; ++ni) {
          const int s = s0 + wn + ni * 16 + fr;
          const float ek = __expf(acck[mi][ni][r] + bkv);
          const float vv = accv[mi][ni][r] + bvv;
          const size_t idx = ((size_t)b * 512 + d) * 1024 + s;
          ekT[idx]  = f2bf(ek);
          ekvT[idx] = f2bf(ek * vv);
        }
      }
  }
}

// ---------- AFT mixing: out = sigq * (EW@ekv) / (EW@ek), per batch ----------
__global__ __launch_bounds__(256, 2) void aft_kernel(const u16* __restrict__ ew,
                                                     const u16* __restrict__ ekT,
                                                     const u16* __restrict__ ekvT,
                                                     float* __restrict__ out) {
  __shared__ __align__(16) u16 As[128 * 64];
  __shared__ __align__(16) u16 B1[128 * 64];
  __shared__ __align__(16) u16 B2[128 * 64];
  const int tid = threadIdx.x;
  const int lane = tid & 63, wv = tid >> 6;
  const int wm = (wv & 1) * 64, wn = (wv >> 1) * 64;
  const int fr = lane & 15, quad = lane >> 4;
  const int d0 = blockIdx.x * 128;   // n: feature dim (512)
  const int t0 = blockIdx.y * 128;   // m: target pos (1024)
  const int b  = blockIdx.z;
  f32x4 accn[4][4] = {}, accd[4][4] = {};
  for (int k0 = 0; k0 < 1024; k0 += 64) {
    stage_tile64(ew + (size_t)t0 * 1024 + k0, 1024, As, tid);
    stage_tile64(ekvT + ((size_t)b * 512 + d0) * 1024 + k0, 1024, B1, tid);
    stage_tile64(ekT + ((size_t)b * 512 + d0) * 1024 + k0, 1024, B2, tid);
    __syncthreads();
#pragma unroll
    for (int kk = 0; kk < 2; ++kk) {
      frag8 a[4], b1[4], b2[4];
#pragma unroll
      for (int i = 0; i < 4; ++i) {
        a[i]  = frag_read64(As, wm + i * 16 + fr, kk, quad);
        b1[i] = frag_read64(B1, wn + i * 16 + fr, kk, quad);
        b2[i] = frag_read64(B2, wn + i * 16 + fr, kk, quad);
      }
#pragma unroll
      for (int mi = 0; mi < 4; ++mi)
#pragma unroll
        for (int ni = 0; ni < 4; ++ni) {
          accn[mi][ni] = __builtin_amdgcn_mfma_f32_16x16x32_bf16(a[mi], b1[ni], accn[mi][ni], 0, 0, 0);
          accd[mi][ni] = __builtin_amdgcn_mfma_f32_16x16x32_bf16(a[mi], b2[ni], accd[mi][ni], 0, 0, 0);
        }
    }
    __syncthreads();
  }
#pragma unroll
  for (int mi = 0; mi < 4; ++mi)
#pragma unroll
    for (int ni = 0; ni < 4; ++ni)
#pragma unroll
      for (int r = 0; r < 4; ++r) {
        const int t = t0 + wm + mi * 16 + quad * 4 + r;
        const int d = d0 + wn + ni * 16 + fr;
        const size_t idx = ((size_t)b * 1024 + t) * 512 + d;
        const float sq = out[idx];                    // sigmoid(q) from qkv Q path
        out[idx] = sq * accn[mi][ni][r] / accd[mi][ni][r];
      }
}

// ---------- launch ----------
// Workspace layout (bytes):
//   xb   bf16[32768][512]      @ 0          (32 MB)
//   wqb  bf16[512][512]        @ 33554432
//   wkb                        @ 34078720
//   wvb                        @ 34603008
//   ewb  bf16[1024][1024]      @ 35127296   (2 MB)
//   ekT  bf16[32][512][1024]   @ 37224448   (32 MB)
//   ekvT bf16[32][512][1024]   @ 70778880   (32 MB)
// total ≈ 99.5 MB. sigmoid(q) lives in d_out (read-then-overwrite in aft_kernel).
extern "C" void kernel_launch(void* const* d_in, const int* in_sizes, int n_in,
                              void* d_out, int out_size, void* d_ws, size_t ws_size,
                              hipStream_t stream) {
  const float* x  = (const float*)d_in[0];
  const float* Wq = (const float*)d_in[1];
  const float* bq = (const float*)d_in[2];
  const float* Wk = (const float*)d_in[3];
  const float* bk = (const float*)d_in[4];
  const float* Wv = (const float*)d_in[5];
  const float* bv = (const float*)d_in[6];
  const float* pb = (const float*)d_in[7];
  float* out = (float*)d_out;
  char* ws = (char*)d_ws;
  u16* xb   = (u16*)(ws);
  u16* wqb  = (u16*)(ws + 33554432);
  u16* wkb  = (u16*)(ws + 34078720);
  u16* wvb  = (u16*)(ws + 34603008);
  u16* ewb  = (u16*)(ws + 35127296);
  u16* ekT  = (u16*)(ws + 37224448);
  u16* ekvT = (u16*)(ws + 70778880);

  prep_kernel<<<18176, 256, 0, stream>>>(x, Wq, Wk, Wv, pb, xb, wqb, wkb, wvb, ewb);
  qkv_kernel<<<2048, 256, 0, stream>>>(xb, wqb, wkb, wvb, bq, bk, bv, out, ekT, ekvT);
  aft_kernel<<<dim3(4, 8, 32), 256, 0, stream>>>(ewb, ekT, ekvT, out);
}